// Round 1
// baseline (488.951 us; speedup 1.0000x reference)
//
#include <hip/hip_runtime.h>
#include <hip/hip_bf16.h>
#include <cmath>
#include <cstdint>

typedef short s16x8 __attribute__((ext_vector_type(8)));
typedef unsigned short u16x8 __attribute__((ext_vector_type(8)));
typedef unsigned short u16x4 __attribute__((ext_vector_type(4)));
typedef float f32x4 __attribute__((ext_vector_type(4)));

__device__ __forceinline__ float bf2f(uint16_t u) {
  union { uint32_t i; float f; } c; c.i = ((uint32_t)u) << 16; return c.f;
}
__device__ __forceinline__ uint16_t f2bf(float f) {
  union { float f; uint32_t i; } c; c.f = f;
  return (uint16_t)((c.i + 0x7FFFu + ((c.i >> 16) & 1u)) >> 16);
}
// packed f32x2 -> bf16x2 (RNE), low word = a
__device__ __forceinline__ uint32_t pkbf(float a, float b) {
  union { __hip_bfloat162 h; uint32_t u; } c;
  c.h = __float22bfloat162_rn(float2{a, b});
  return c.u;
}

// async global->LDS, 16B/lane; lane i lands at (uniform base) + 16*i
__device__ __forceinline__ void gload16(const void* g, void* l) {
  __builtin_amdgcn_global_load_lds(
      (const __attribute__((address_space(1))) void*)g,
      (__attribute__((address_space(3))) void*)l, 16, 0, 0);
}

// ---- dtype sniff: bf16 data -> even 16-bit words have sane exponents ----
__device__ __forceinline__ bool sniff_is_bf16(const uint16_t* u16, int64_t n,
                                              int tid, int* s_cnt) {
  int cnt = 0;
#pragma unroll
  for (int j = 0; j < 4; j++) {
    int64_t idx = (((int64_t)(tid * 4 + j)) * 2) % n;
    idx &= ~(int64_t)1;
    uint32_t e = (u16[idx] >> 7) & 0xFF;
    cnt += (e >= 96 && e <= 144) ? 1 : 0;
  }
  if (tid == 0) *s_cnt = 0;
  __syncthreads();
  atomicAdd(s_cnt, cnt);
  __syncthreads();
  return (*s_cnt) * 10 > 1024 * 6;
}

// ------ ONE fused prep dispatch (all paths vectorized, 16B/lane) -----------
// [0,1024): zero d_out(16MB, f32x4 x4); [1024,2048): cvt x; [2048,4096): cvt ctx;
// 4096..4098: biases; [4099,5123): 64x64 transposes Wq/Wk/Wv/Wo;
// [5123,6147): W1; [6147,7171): W2.
__global__ __launch_bounds__(256) void prep_all(
    float* dout,
    const void* xr, const void* cr, const void* bor, const void* b1r, const void* b2r,
    const void* Wq, const void* Wk, const void* Wv, const void* Wo,
    const void* W1, const void* W2,
    uint16_t* xo, uint16_t* co, uint16_t* boo, uint16_t* b1o, uint16_t* b2o,
    uint16_t* WqT, uint16_t* WkT, uint16_t* WvT, uint16_t* WoT,
    uint16_t* W1T, uint16_t* W2T) {
  __shared__ int s_cnt;
  __shared__ uint16_t tile[64][65];
  const int id = blockIdx.x;
  const int tid = threadIdx.x;

  if (id < 1024) {  // zero d_out: 4 x f32x4 per thread
    float* p = dout + ((int64_t)id * 256 + tid) * 4;
#pragma unroll
    for (int i = 0; i < 4; i++)
      *(f32x4*)(p + (int64_t)i * 262144) = (f32x4){0.f, 0.f, 0.f, 0.f};
    return;
  }
  if (id < 4099) {  // vectorized converts
    const void* src; uint16_t* dst; int64_t tot; int64_t base; int nv;
    if (id < 2048)      { src = xr; dst = xo; tot = 4194304; base = (int64_t)(id - 1024) * 4096; nv = 4; }
    else if (id < 4096) { src = cr; dst = co; tot = 8388608; base = (int64_t)(id - 2048) * 4096; nv = 4; }
    else if (id == 4096){ src = bor; dst = boo; tot = 1024; base = 0; nv = 1; }
    else if (id == 4097){ src = b1r; dst = b1o; tot = 4096; base = 0; nv = 4; }
    else                { src = b2r; dst = b2o; tot = 1024; base = 0; nv = 1; }
    const bool is16 = sniff_is_bf16((const uint16_t*)src, tot, tid, &s_cnt);
    if (is16) {  // already bf16: copy 8B/lane
      const uint64_t* s = (const uint64_t*)((const uint16_t*)src + base);
      uint64_t* d = (uint64_t*)(dst + base);
      for (int i = 0; i < nv; i++) d[i * 256 + tid] = s[i * 256 + tid];
    } else {  // fp32 -> bf16: float4 load, packed cvt, 8B store
      const f32x4* s = (const f32x4*)((const float*)src + base);
      uint2* d = (uint2*)(dst + base);
      for (int i = 0; i < nv; i++) {
        f32x4 v = s[i * 256 + tid];
        uint2 o; o.x = pkbf(v[0], v[1]); o.y = pkbf(v[2], v[3]);
        d[i * 256 + tid] = o;
      }
    }
    return;
  }
  // 64x64 fp32->bf16 transposes: in[R][C] -> out[C][R]
  const int t0 = id - 4099;
  const void* src; uint16_t* dst; int R, C, bx, by;
  if (t0 < 1024) {  // Wq/Wk/Wv/Wo, 256 tiles each (16x16)
    const int wsel = t0 >> 8, t = t0 & 255;
    const void* srcs[4] = {Wq, Wk, Wv, Wo};
    uint16_t* dsts[4] = {WqT, WkT, WvT, WoT};
    src = srcs[wsel]; dst = dsts[wsel]; R = 1024; C = 1024; bx = t & 15; by = t >> 4;
  } else if (t0 < 2048) { int t = t0 - 1024; src = W1; dst = W1T; R = 1024; C = 4096; bx = t & 63; by = t >> 6; }
  else                  { int t = t0 - 2048; src = W2; dst = W2T; R = 4096; C = 1024; bx = t & 15; by = t >> 4; }
  const uint16_t* u16 = (const uint16_t*)src;
  const float* f32 = (const float*)src;
  const bool is16 = sniff_is_bf16(u16, (int64_t)R * C, tid, &s_cnt);
  const int c0 = bx * 64, r0 = by * 64;
  // load 16B/lane + transpose-scatter into LDS (b16, <=2-way banks)
  if (is16) {
    const int c8 = (tid & 7) * 8, r = tid >> 3;  // 32 rows/pass, 2 passes
#pragma unroll
    for (int ri = 0; ri < 2; ri++) {
      const int row = r + ri * 32;
      u16x8 v = *(const u16x8*)(u16 + (int64_t)(r0 + row) * C + c0 + c8);
#pragma unroll
      for (int j = 0; j < 8; j++) tile[c8 + j][row] = v[j];
    }
  } else {
    const int c4 = (tid & 15) * 4, r = tid >> 4;  // 16 rows/pass, 4 passes
#pragma unroll
    for (int ri = 0; ri < 4; ri++) {
      const int row = r + ri * 16;
      f32x4 v = *(const f32x4*)(f32 + (int64_t)(r0 + row) * C + c0 + c4);
#pragma unroll
      for (int j = 0; j < 4; j++) tile[c4 + j][row] = f2bf(v[j]);
    }
  }
  __syncthreads();
  // write 16B/lane contiguous
  const int rr8 = (tid & 7) * 8, cc = tid >> 3;
#pragma unroll
  for (int ci = 0; ci < 2; ci++) {
    const int col = cc + ci * 32;
    *(u16x8*)(dst + (int64_t)(c0 + col) * R + r0 + rr8) = *(const u16x8*)&tile[col][rr8];
  }
}

// ---- per-batch V transpose (vectorized): KVb[b*2048+k][1024+c] -> Vt[b][c][k]
// grid (16, 32, 4): 64x64 bf16 tiles, 16B reads + 16B writes.
__global__ __launch_bounds__(256) void vtrans(
    const uint16_t* __restrict__ KVb, uint16_t* __restrict__ Vt) {
  __shared__ uint16_t tile[64][65];
  const int z = blockIdx.z;
  const uint16_t* in = KVb + (int64_t)z * 2048 * 2048 + 1024;  // [2048 k][1024 c] stride 2048
  uint16_t* out = Vt + (int64_t)z * 1024 * 2048;               // [1024 c][2048 k]
  const int tid = threadIdx.x;
  const int c0 = blockIdx.x * 64, k0 = blockIdx.y * 64;
  const int c8 = (tid & 7) * 8, r = tid >> 3;
#pragma unroll
  for (int ri = 0; ri < 2; ri++) {
    const int krow = r + ri * 32;
    u16x8 v = *(const u16x8*)(in + (int64_t)(k0 + krow) * 2048 + c0 + c8);
#pragma unroll
    for (int j = 0; j < 8; j++) tile[c8 + j][krow] = v[j];
  }
  __syncthreads();
  const int k8 = (tid & 7) * 8, cc = tid >> 3;
#pragma unroll
  for (int ci = 0; ci < 2; ci++) {
    const int col = cc + ci * 32;
    *(u16x8*)(out + (int64_t)(c0 + col) * 2048 + k0 + k8) = *(const u16x8*)&tile[col][k8];
  }
}

enum { EPI_NONE = 0, EPI_BIAS_RES = 1, EPI_BIAS_GELU = 2 };

// ---------------- GEMM v4 (legacy 128x128, kept for out-proj) -------------
#define BM 128
#define BN 128
#define BK 64

template <int EPI, int RESF32, int OUTF32, int SPLITK>
__device__ __forceinline__ void gemm_body(
    const uint16_t* __restrict__ A, const uint16_t* __restrict__ Bt,
    void* __restrict__ Cv, const uint16_t* __restrict__ bias,
    const void* __restrict__ resid, int M, int N, int K_total,
    int m0, int n0, int zslice, uint16_t* As, uint16_t* Bs) {
  const int tid = threadIdx.x;
  const int w = tid >> 6, l = tid & 63;
  const int wu = __builtin_amdgcn_readfirstlane(w);
  const int wm = (w >> 1) * 64, wn = (w & 1) * 64;
  const int ls = l & 15, lg = l >> 4;
  const int K = SPLITK ? (K_total >> 1) : K_total;
  const int kof = SPLITK ? zslice * K : 0;

  const int sr = 8 * w + (l >> 3);
  const int koff = (((l & 7) ^ ((l >> 3) & 7)) * 8);
  const uint16_t* Ag = A + (int64_t)(m0 + sr) * K_total + kof + koff;
  const uint16_t* Bg = Bt + (int64_t)(n0 + sr) * K_total + kof + koff;
  const int64_t rstep = (int64_t)32 * K_total;

  uint16_t* lA = As + wu * 512;
  uint16_t* lB = Bs + wu * 512;

  f32x4 acc[4][4] = {};

  for (int kb = 0; kb < K; kb += BK) {
    __syncthreads();
#pragma unroll
    for (int r = 0; r < 4; r++) {
      gload16(Ag + r * rstep + kb, lA + r * 2048);
      gload16(Bg + r * rstep + kb, lB + r * 2048);
    }
    __syncthreads();
#pragma unroll
    for (int kk = 0; kk < 2; kk++) {
      s16x8 af[4], bfr[4];
#pragma unroll
      for (int i = 0; i < 4; i++) {
        const int row = wm + i * 16 + ls;
        af[i] = *(const s16x8*)&As[row * 64 + (((kk * 4 + lg) ^ (ls & 7)) * 8)];
      }
#pragma unroll
      for (int j = 0; j < 4; j++) {
        const int row = wn + j * 16 + ls;
        bfr[j] = *(const s16x8*)&Bs[row * 64 + (((kk * 4 + lg) ^ (ls & 7)) * 8)];
      }
#pragma unroll
      for (int i = 0; i < 4; i++)
#pragma unroll
        for (int j = 0; j < 4; j++)
          acc[i][j] = __builtin_amdgcn_mfma_f32_16x16x32_bf16(af[i], bfr[j], acc[i][j], 0, 0, 0);
    }
  }

#pragma unroll
  for (int i = 0; i < 4; i++) {
#pragma unroll
    for (int rr = 0; rr < 4; rr++) {
      const int64_t row = m0 + wm + i * 16 + lg * 4 + rr;
#pragma unroll
      for (int j = 0; j < 4; j++) {
        const int col = n0 + wn + j * 16 + ls;
        float v = acc[i][j][rr];
        if (EPI == EPI_BIAS_RES) {
          if (!SPLITK || zslice == 0) {
            const float rv = RESF32 ? ((const float*)resid)[row * N + col]
                                    : bf2f(((const uint16_t*)resid)[row * N + col]);
            v += bf2f(bias[col]) + rv;
          }
        } else if (EPI == EPI_BIAS_GELU) {
          v += bf2f(bias[col]);
          v = 0.5f * v * (1.0f + erff(v * 0.70710678118654752f));  // exact GELU
        }
        if (SPLITK)
          atomicAdd((float*)Cv + row * N + col, v);
        else if (OUTF32)
          ((float*)Cv)[row * N + col] = v;
        else
          ((uint16_t*)Cv)[row * N + col] = f2bf(v);
      }
    }
  }
}

template <int EPI, int RESF32, int OUTF32, int SPLITK>
__global__ __launch_bounds__(256, 3) void gemm_single(
    const uint16_t* __restrict__ A, const uint16_t* __restrict__ Bt,
    void* __restrict__ Cv, const uint16_t* __restrict__ bias,
    const void* __restrict__ resid, int M, int N, int K_total) {
  __shared__ alignas(16) uint16_t As[BM * BK];
  __shared__ alignas(16) uint16_t Bs[BN * BK];
  gemm_body<EPI, RESF32, OUTF32, SPLITK>(A, Bt, Cv, bias, resid, M, N, K_total,
                                         blockIdx.x * BM, blockIdx.y * BN,
                                         (int)blockIdx.z, As, Bs);
}

// ============ GEMM v5: 256x256 tile, BK=64, 8-wave, 8-phase pipeline ======
// 512 threads = 8 waves (2M x 4N); per-wave output 128x64 (8x4 16x16 frags).
// LDS 128KB: A[2][256][64] + B[2][256][64] bf16, XOR-chunk-swizzled rows.
// Per K-tile: 4 phases, each = {12 ds_read_b128, 1 half-tile global_load_lds
// prefetch, s_barrier, lgkmcnt(0), setprio(1), 16 MFMA, setprio(0), [counted
// vmcnt], s_barrier}.  Stage order per tile t (into buf t+1&1, for tile t+1):
//   q0: B0,B1   q1: B2,B3 + vmcnt(4)   q2: A0,A2   q3: A1,A3 + vmcnt(2)
// Derivation (per-wave ticks, 1/stage-call):
//   q1 vmcnt(4): outstanding = {prev A0,A2,A1,A3} + {B0..B3} ; leaves the 4 B's
//     -> THIS tile's A1,A3 (read at q2/q3) are landed.
//   q3 vmcnt(2): outstanding = 8 stages of tile t+1; leaves {A1,A3}
//     -> next tile's B (all waves, phase0) + A0,A2 (qm=0 reads) are landed.
// Never vmcnt(0) in the loop; raw s_barrier (no __syncthreads drain).
#define G8K 64

#define STAGE_A8(BB, Q, KB) \
  gload16(Ag + (int64_t)(Q) * cstep + (KB), As + (BB) + (Q) * 4096 + wu * 512)
#define STAGE_B8(BB, Q, KB) \
  gload16(Bg + (int64_t)(Q) * cstep + (KB), Bs + (BB) + (Q) * 4096 + wu * 512)

#define PHASE8(QM, QN, S0, S1, WAITC)                                          \
  do {                                                                         \
    s16x8 a0_[4], a1_[4], b0_[2], b1_[2];                                      \
    const int x_ = (ls & 7);                                                   \
    _Pragma("unroll") for (int i_ = 0; i_ < 4; i_++) {                         \
      const int r_ = wm + (QM) * 64 + i_ * 16 + ls;                            \
      a0_[i_] = *(const s16x8*)&As[cb + r_ * 64 + ((lg ^ x_) * 8)];            \
      a1_[i_] = *(const s16x8*)&As[cb + r_ * 64 + (((4 + lg) ^ x_) * 8)];      \
    }                                                                          \
    _Pragma("unroll") for (int j_ = 0; j_ < 2; j_++) {                         \
      const int r_ = wn + (QN) * 32 + j_ * 16 + ls;                            \
      b0_[j_] = *(const s16x8*)&Bs[cb + r_ * 64 + ((lg ^ x_) * 8)];            \
      b1_[j_] = *(const s16x8*)&Bs[cb + r_ * 64 + (((4 + lg) ^ x_) * 8)];      \
    }                                                                          \
    S0; S1;                                                                    \
    __builtin_amdgcn_s_barrier();                                              \
    asm volatile("s_waitcnt lgkmcnt(0)" ::: "memory");                         \
    __builtin_amdgcn_s_setprio(1);                                             \
    _Pragma("unroll") for (int i_ = 0; i_ < 4; i_++)                           \
      _Pragma("unroll") for (int j_ = 0; j_ < 2; j_++) {                       \
        acc[(QM)*4 + i_][(QN)*2 + j_] = __builtin_amdgcn_mfma_f32_16x16x32_bf16( \
            a0_[i_], b0_[j_], acc[(QM)*4 + i_][(QN)*2 + j_], 0, 0, 0);         \
        acc[(QM)*4 + i_][(QN)*2 + j_] = __builtin_amdgcn_mfma_f32_16x16x32_bf16( \
            a1_[i_], b1_[j_], acc[(QM)*4 + i_][(QN)*2 + j_], 0, 0, 0);         \
      }                                                                        \
    __builtin_amdgcn_s_setprio(0);                                             \
    WAITC;                                                                     \
    __builtin_amdgcn_s_barrier();                                              \
  } while (0)

template <int EPI, int RESF32, int OUTF32, int SPLITK>
__device__ __forceinline__ void gemm8_body(
    const uint16_t* __restrict__ A, const uint16_t* __restrict__ Bt,
    void* __restrict__ Cv, const uint16_t* __restrict__ bias,
    const void* __restrict__ resid, int M, int N, int K_total,
    int m0, int n0, int zslice, uint16_t* As, uint16_t* Bs) {
  const int tid = threadIdx.x;
  const int w = tid >> 6, l = tid & 63;
  const int wu = __builtin_amdgcn_readfirstlane(w);
  const int ls = l & 15, lg = l >> 4;
  const int wm = (w >> 2) * 128, wn = (w & 3) * 64;
  const int K = K_total / SPLITK;
  const int kof = zslice * K;
  const int NT = K / G8K;

  // staging: per call-region q (64 rows), thread covers row q*64 + w*8 + l/8,
  // LDS chunk position (l&7) <- logical chunk (l&7)^(row&7) (XOR swizzle).
  const int srow = (w << 3) + (l >> 3);
  const int koff = (((l & 7) ^ ((l >> 3) & 7)) * 8);
  const uint16_t* Ag = A + (int64_t)(m0 + srow) * K_total + kof + koff;
  const uint16_t* Bg = Bt + (int64_t)(n0 + srow) * K_total + kof + koff;
  const int64_t cstep = (int64_t)64 * K_total;

  f32x4 acc[8][4] = {};

  // prologue: tile 0 -> buf0 in steady-state order; leave A1,A3 in flight
  STAGE_B8(0, 0, 0); STAGE_B8(0, 1, 0); STAGE_B8(0, 2, 0); STAGE_B8(0, 3, 0);
  STAGE_A8(0, 0, 0); STAGE_A8(0, 2, 0); STAGE_A8(0, 1, 0); STAGE_A8(0, 3, 0);
  asm volatile("s_waitcnt vmcnt(2)" ::: "memory");
  __builtin_amdgcn_s_barrier();

  for (int t = 0; t < NT; ++t) {
    const int cb = (t & 1) << 14;   // current buf element base (x16384)
    const int nb = 16384 - cb;      // next buf
    // last tile wraps prefetch to kb=0 (harmless; keeps vmcnt counts uniform)
    const int64_t kbn = (t + 1 < NT) ? (int64_t)(t + 1) * G8K : 0;
    PHASE8(0, 0, STAGE_B8(nb, 0, kbn), STAGE_B8(nb, 1, kbn), (void)0);
    PHASE8(0, 1, STAGE_B8(nb, 2, kbn), STAGE_B8(nb, 3, kbn),
           asm volatile("s_waitcnt vmcnt(4)" ::: "memory"));
    PHASE8(1, 0, STAGE_A8(nb, 0, kbn), STAGE_A8(nb, 2, kbn), (void)0);
    PHASE8(1, 1, STAGE_A8(nb, 1, kbn), STAGE_A8(nb, 3, kbn),
           asm volatile("s_waitcnt vmcnt(2)" ::: "memory"));
  }

#pragma unroll
  for (int i = 0; i < 8; i++) {
#pragma unroll
    for (int rr = 0; rr < 4; rr++) {
      const int64_t row = m0 + wm + i * 16 + lg * 4 + rr;
#pragma unroll
      for (int j = 0; j < 4; j++) {
        const int col = n0 + wn + j * 16 + ls;
        float v = acc[i][j][rr];
        if (EPI == EPI_BIAS_RES) {
          if (SPLITK == 1 || zslice == 0) {
            const float rv = RESF32 ? ((const float*)resid)[row * N + col]
                                    : bf2f(((const uint16_t*)resid)[row * N + col]);
            v += bf2f(bias[col]) + rv;
          }
        } else if (EPI == EPI_BIAS_GELU) {
          v += bf2f(bias[col]);
          v = 0.5f * v * (1.0f + erff(v * 0.70710678118654752f));  // exact GELU
        }
        if (SPLITK > 1)
          atomicAdd((float*)Cv + row * N + col, v);
        else if (OUTF32)
          ((float*)Cv)[row * N + col] = v;
        else
          ((uint16_t*)Cv)[row * N + col] = f2bf(v);
      }
    }
  }
}

template <int EPI, int RESF32, int OUTF32, int SPLITK>
__global__ __launch_bounds__(512, 2) void gemm8_single(
    const uint16_t* __restrict__ A, const uint16_t* __restrict__ Bt,
    void* __restrict__ Cv, const uint16_t* __restrict__ bias,
    const void* __restrict__ resid, int M, int N, int K_total) {
  __shared__ alignas(16) uint16_t As[2 * 16384];  // 64KB
  __shared__ alignas(16) uint16_t Bs[2 * 16384];  // 64KB
  gemm8_body<EPI, RESF32, OUTF32, SPLITK>(A, Bt, Cv, bias, resid, M, N, K_total,
                                          blockIdx.x * 256, blockIdx.y * 256,
                                          (int)blockIdx.z, As, Bs);
}

// grouped Q-proj + KV-proj at 256x256: blocks [0,256) KV, [256,320) Q.
__global__ __launch_bounds__(512, 2) void gemm8_qkv(
    const uint16_t* __restrict__ xA, const uint16_t* __restrict__ WqT,
    uint16_t* __restrict__ Qb,
    const uint16_t* __restrict__ ctxA, const uint16_t* __restrict__ KVWt,
    uint16_t* __restrict__ KVb) {
  __shared__ alignas(16) uint16_t As[2 * 16384];
  __shared__ alignas(16) uint16_t Bs[2 * 16384];
  const int id = blockIdx.x;
  if (id < 256) {
    gemm8_body<EPI_NONE, 0, 0, 1>(ctxA, KVWt, KVb, nullptr, nullptr, 8192, 2048, 1024,
                                  (id & 31) * 256, (id >> 5) * 256, 0, As, Bs);
  } else {
    const int t = id - 256;
    gemm8_body<EPI_NONE, 0, 0, 1>(xA, WqT, Qb, nullptr, nullptr, 4096, 1024, 1024,
                                  (t & 15) * 256, (t >> 4) * 256, 0, As, Bs);
  }
}

// ---------------- flash cross-attention v5 (unchanged) --------------------
#define KLD 72
#define PLD 72

__global__ __launch_bounds__(256, 2) void attn_kernel(
    const uint16_t* __restrict__ Q,   // [B*1024][1024]
    const uint16_t* __restrict__ KV,  // [B*2048][2048]; cols 0..1023 = K
    const uint16_t* __restrict__ Vt,  // [B][1024 (h*64+d)][2048 (key)]
    uint16_t* __restrict__ O) {       // [B*1024][1024]
  __shared__ alignas(16) uint16_t Ks[64 * KLD];
  __shared__ alignas(16) uint16_t Vts[64 * KLD];
  __shared__ alignas(16) uint16_t Ps[8][16 * PLD];  // [w*2+qq]

  const int tid = threadIdx.x;
  const int w = tid >> 6, l = tid & 63;
  const int ls = l & 15, lg = l >> 4;

  const int blk = blockIdx.x;
  const int bh = blk & 63;   // XCD = bh%8 for all 8 q-blocks of this (b,h)
  const int qb = blk >> 6;   // 0..7
  const int h = bh & 15, b = bh >> 4;

  const int64_t qrow0 = (int64_t)b * 1024 + qb * 128;
  const int hoff = h * 64;
  const uint16_t* Vtb = Vt + (int64_t)b * 1024 * 2048;

  const float sc = 0.125f * 1.4426950408889634f;  // scale * log2(e)

  s16x8 qf[2][2];
#pragma unroll
  for (int qq = 0; qq < 2; qq++)
#pragma unroll
    for (int ks = 0; ks < 2; ks++) {
      s16x8 r = *(const s16x8*)(Q + (qrow0 + w * 32 + qq * 16 + ls) * 1024 + hoff + ks * 32 + lg * 8);
#pragma unroll
      for (int j = 0; j < 8; j++)
        qf[qq][ks][j] = (short)f2bf(bf2f((uint16_t)r[j]) * sc);
    }

  f32x4 oacc[2][4] = {};
  float lsum[2] = {0.f, 0.f};

  const int srow = tid >> 3;      // 0..31
  const int sc8 = (tid & 7) * 8;  // 0..56
  const uint16_t* Kg = KV + ((int64_t)b * 2048 + srow) * 2048 + hoff + sc8;
  const uint16_t* Vg = Vtb + (int64_t)(hoff + srow) * 2048 + sc8;

  s16x8 rk0 = *(const s16x8*)(Kg);
  s16x8 rk1 = *(const s16x8*)(Kg + (int64_t)32 * 2048);
  s16x8 rv0 = *(const s16x8*)(Vg);
  s16x8 rv1 = *(const s16x8*)(Vg + (int64_t)32 * 2048);

  for (int kt = 0; kt < 2048; kt += 64) {
    __syncthreads();
    *(s16x8*)&Ks[srow * KLD + sc8] = rk0;
    *(s16x8*)&Ks[(srow + 32) * KLD + sc8] = rk1;
    *(s16x8*)&Vts[srow * KLD + sc8] = rv0;
    *(s16x8*)&Vts[(srow + 32) * KLD + sc8] = rv1;
    const int ktn = kt + 64;
    if (ktn < 2048) {
      rk0 = *(const s16x8*)(Kg + (int64_t)ktn * 2048);
      rk1 = *(const s16x8*)(Kg + (int64_t)(ktn + 32) * 2048);
      rv0 = *(const s16x8*)(Vg + ktn);
      rv1 = *(const s16x8*)(Vg + ktn + (int64_t)32 * 2048);
    }
    __syncthreads();

    f32x4 st[2][4];
#pragma unroll
    for (int jn = 0; jn < 4; jn++) {
      f32x4 z = {0.f, 0.f, 0.f, 0.f};
      st[0][jn] = z; st[1][jn] = z;
#pragma unroll
      for (int ks = 0; ks < 2; ks++) {
        s16x8 kf = *(const s16x8*)&Ks[(jn * 16 + ls) * KLD + ks * 32 + lg * 8];
        st[0][jn] = __builtin_amdgcn_mfma_f32_16x16x32_bf16(kf, qf[0][ks], st[0][jn], 0, 0, 0);
        st[1][jn] = __builtin_amdgcn_mfma_f32_16x16x32_bf16(kf, qf[1][ks], st[1][jn], 0, 0, 0);
      }
    }

#pragma unroll
    for (int qq = 0; qq < 2; qq++)
#pragma unroll
      for (int jn = 0; jn < 4; jn++) {
        const float p0 = exp2f(st[qq][jn][0]);
        const float p1 = exp2f(st[qq][jn][1]);
        const float p2 = exp2f(st[qq][jn][2]);
        const float p3 = exp2f(st[qq][jn][3]);
        lsum[qq] += (p0 + p1) + (p2 + p3);
        uint2 pk; pk.x = pkbf(p0, p1); pk.y = pkbf(p2, p3);
        *(uint2*)&Ps[w * 2 + qq][ls * PLD + jn * 16 + lg * 4] = pk;
      }

#pragma unroll
    for (int ks = 0; ks < 2; ks++) {
      s16x8 pf0 = *(const s16x8*)&Ps[w * 2 + 0][ls * PLD + ks * 32 + lg * 8];
      s16x8 pf1 = *(const s16x8*)&Ps[w * 2 + 1][ls * PLD + ks * 32 + lg * 8];
#pragma unroll
      for (int jn = 0; jn < 4; jn++) {
        s16x8 vf = *(const s16x8*)&Vts[(jn * 16 + ls) * KLD + ks * 32 + lg * 8];
        oacc[0][jn] = __builtin_amdgcn_mfma_f32_16x16x32_bf16(pf0, vf, oacc[0][jn], 0, 0, 0);
        oacc[1][jn] = __builtin_amdgcn_mfma_f32_16x16x32_bf16(pf1, vf, oacc[1][jn], 0, 0, 0);
      }
    }
  }

#pragma unroll
  for (int qq = 0; qq < 2; qq++) {
    float red = lsum[qq];
    red += __shfl_xor(red, 16, 64);
    red += __shfl_xor(red, 32, 64);
#pragma unroll
    for (int rr = 0; rr < 4; rr++) {
      const float inv = 1.0f / __shfl(red, lg * 4 + rr, 64);
      const int64_t row = qrow0 + w * 32 + qq * 16 + lg * 4 + rr;
#pragma unroll
      for (int jn = 0; jn < 4; jn++)
        O[row * 1024 + hoff + jn * 16 + ls] = f2bf(oacc[qq][jn][rr] * inv);
    }
  }
}

// ---------------- host ----------------
extern "C" void kernel_launch(void* const* d_in, const int* in_sizes, int n_in,
                              void* d_out, int out_size, void* d_ws, size_t ws_size,
                              hipStream_t stream) {
  const void* x_raw   = d_in[0];
  const void* ctx_raw = d_in[1];
  const void* Wq_raw  = d_in[2];
  const void* Wk_raw  = d_in[3];
  const void* Wv_raw  = d_in[4];
  const void* Wo_raw  = d_in[5];
  const void* bo_raw  = d_in[6];
  const void* W1_raw  = d_in[7];
  const void* b1_raw  = d_in[8];
  const void* W2_raw  = d_in[9];
  const void* b2_raw  = d_in[10];

  const int64_t Mi = 1 << 20;
  uint16_t* ws   = (uint16_t*)d_ws;
  uint16_t* WqT  = ws;                  // [0,1M)
  uint16_t* KVWt = ws + 1 * Mi;         // [1M,3M)  [2048][1024] = [WkT;WvT]
  uint16_t* WoT  = ws + 3 * Mi;         // [3M,4M)
  uint16_t* W1T  = ws + 4 * Mi;         // [4M,8M)   [4096][1024]
  uint16_t* W2T  = ws + 8 * Mi;         // [8M,12M)  [1024][4096]
  uint16_t* bob  = ws + 12 * Mi;
  uint16_t* b1b  = ws + 12 * Mi + 1024;
  uint16_t* b2b  = ws + 12 * Mi + 5120;
  uint16_t* xb   = ws + 13 * Mi;        // [13M,17M) dead after Q-proj
  uint16_t* AO   = ws + 13 * Mi;        // alias xb (born in attention)
  uint16_t* ctxb = ws + 17 * Mi;        // [17M,25M) dead after KV-proj
  uint16_t* Vt   = ws + 17 * Mi;        // alias ctxb (born after KV-proj)
  uint16_t* X1   = ws + 17 * Mi;        // alias Vt (born after attention)
  uint16_t* Qb   = ws + 25 * Mi;        // [25M,29M)
  uint16_t* KVb  = ws + 29 * Mi;        // [29M,45M) [8192][2048]; dead after attn
  uint16_t* Hb   = ws + 29 * Mi;        // alias KVb (born at FF1)
  // peak ws: 45M elements = 90 MB

  const dim3 tb(256);
  const dim3 tb8(512);
  // one fused prep dispatch (vectorized): zero + converts + 6 transposes
  prep_all<<<dim3(7171), tb, 0, stream>>>(
      (float*)d_out,
      x_raw, ctx_raw, bo_raw, b1_raw, b2_raw,
      Wq_raw, Wk_raw, Wv_raw, Wo_raw, W1_raw, W2_raw,
      xb, ctxb, bob, b1b, b2b,
      WqT, KVWt, KVWt + Mi, WoT, W1T, W2T);

  // grouped Q-proj + fused KV-proj, 256^2 8-phase (320 blocks x 8 waves)
  gemm8_qkv<<<dim3(320), tb8, 0, stream>>>(xb, WqT, Qb, ctxb, KVWt, KVb);

  // per-batch V transpose (vectorized 64x64 tiles)
  vtrans<<<dim3(16, 32, 4), tb, 0, stream>>>(KVb, Vt);

  attn_kernel<<<dim3(512), tb, 0, stream>>>(Qb, KVb, Vt, AO);

  // out-proj + bias + residual(x, fp32 direct): N=1024 -> only 64 tiles at
  // 256^2; keep legacy 128^2 kernel (256 blocks, full GPU)
  gemm_single<EPI_BIAS_RES, 1, 0, 0><<<dim3(32, 8), tb, 0, stream>>>(
      AO, WoT, X1, bob, x_raw, 4096, 1024, 1024);
  // FF1 + bias + exact GELU: 256 blocks, 8-phase
  gemm8_single<EPI_BIAS_GELU, 0, 0, 1><<<dim3(16, 16), tb8, 0, stream>>>(
      X1, W1T, Hb, b1b, nullptr, 4096, 4096, 1024);
  // FF2 + bias + residual(X1): split-K4 (256 blocks), fp32 atomics into
  // pre-zeroed d_out
  gemm8_single<EPI_BIAS_RES, 0, 1, 4><<<dim3(16, 4, 4), tb8, 0, stream>>>(
      Hb, W2T, d_out, b2b, X1, 4096, 1024, 4096);
}

// Round 2
// 419.375 us; speedup vs baseline: 1.1659x; 1.1659x over previous
//
#include <hip/hip_runtime.h>
#include <hip/hip_bf16.h>
#include <cmath>
#include <cstdint>

typedef short s16x8 __attribute__((ext_vector_type(8)));
typedef unsigned short u16x8 __attribute__((ext_vector_type(8)));
typedef unsigned short u16x4 __attribute__((ext_vector_type(4)));
typedef float f32x4 __attribute__((ext_vector_type(4)));

__device__ __forceinline__ float bf2f(uint16_t u) {
  union { uint32_t i; float f; } c; c.i = ((uint32_t)u) << 16; return c.f;
}
__device__ __forceinline__ uint16_t f2bf(float f) {
  union { float f; uint32_t i; } c; c.f = f;
  return (uint16_t)((c.i + 0x7FFFu + ((c.i >> 16) & 1u)) >> 16);
}
// packed f32x2 -> bf16x2 (RNE), low word = a
__device__ __forceinline__ uint32_t pkbf(float a, float b) {
  union { __hip_bfloat162 h; uint32_t u; } c;
  c.h = __float22bfloat162_rn(float2{a, b});
  return c.u;
}

// exact-GELU via A&S 7.1.26 erf (|err|<1.5e-7; negligible vs bf16 rounding)
__device__ __forceinline__ float gelu_exactf(float v) {
  const float x = v * 0.70710678118654752f;
  const float ax = fabsf(x);
  const float t = 1.0f / (1.0f + 0.3275911f * ax);
  const float poly = ((((1.061405429f * t - 1.453152027f) * t + 1.421413741f) * t
                      - 0.284496736f) * t + 0.254829592f) * t;
  const float e = __expf(-x * x);
  float er = 1.0f - poly * e;
  er = copysignf(er, x);
  return 0.5f * v * (1.0f + er);
}

// async global->LDS, 16B/lane; lane i lands at (uniform base) + 16*i
__device__ __forceinline__ void gload16(const void* g, void* l) {
  __builtin_amdgcn_global_load_lds(
      (const __attribute__((address_space(1))) void*)g,
      (__attribute__((address_space(3))) void*)l, 16, 0, 0);
}

// ---- dtype sniff: bf16 data -> even 16-bit words have sane exponents ----
__device__ __forceinline__ bool sniff_is_bf16(const uint16_t* u16, int64_t n,
                                              int tid, int* s_cnt) {
  int cnt = 0;
#pragma unroll
  for (int j = 0; j < 4; j++) {
    int64_t idx = (((int64_t)(tid * 4 + j)) * 2) % n;
    idx &= ~(int64_t)1;
    uint32_t e = (u16[idx] >> 7) & 0xFF;
    cnt += (e >= 96 && e <= 144) ? 1 : 0;
  }
  if (tid == 0) *s_cnt = 0;
  __syncthreads();
  atomicAdd(s_cnt, cnt);
  __syncthreads();
  return (*s_cnt) * 10 > 1024 * 6;
}

// ------ ONE fused prep dispatch (all paths vectorized, 16B/lane) -----------
__global__ __launch_bounds__(256) void prep_all(
    float* dout,
    const void* xr, const void* cr, const void* bor, const void* b1r, const void* b2r,
    const void* Wq, const void* Wk, const void* Wv, const void* Wo,
    const void* W1, const void* W2,
    uint16_t* xo, uint16_t* co, uint16_t* boo, uint16_t* b1o, uint16_t* b2o,
    uint16_t* WqT, uint16_t* WkT, uint16_t* WvT, uint16_t* WoT,
    uint16_t* W1T, uint16_t* W2T) {
  __shared__ int s_cnt;
  __shared__ uint16_t tile[64][65];
  const int id = blockIdx.x;
  const int tid = threadIdx.x;

  if (id < 1024) {  // zero d_out: 4 x f32x4 per thread
    float* p = dout + ((int64_t)id * 256 + tid) * 4;
#pragma unroll
    for (int i = 0; i < 4; i++)
      *(f32x4*)(p + (int64_t)i * 262144) = (f32x4){0.f, 0.f, 0.f, 0.f};
    return;
  }
  if (id < 4099) {  // vectorized converts
    const void* src; uint16_t* dst; int64_t tot; int64_t base; int nv;
    if (id < 2048)      { src = xr; dst = xo; tot = 4194304; base = (int64_t)(id - 1024) * 4096; nv = 4; }
    else if (id < 4096) { src = cr; dst = co; tot = 8388608; base = (int64_t)(id - 2048) * 4096; nv = 4; }
    else if (id == 4096){ src = bor; dst = boo; tot = 1024; base = 0; nv = 1; }
    else if (id == 4097){ src = b1r; dst = b1o; tot = 4096; base = 0; nv = 4; }
    else                { src = b2r; dst = b2o; tot = 1024; base = 0; nv = 1; }
    const bool is16 = sniff_is_bf16((const uint16_t*)src, tot, tid, &s_cnt);
    if (is16) {  // already bf16: copy 8B/lane
      const uint64_t* s = (const uint64_t*)((const uint16_t*)src + base);
      uint64_t* d = (uint64_t*)(dst + base);
      for (int i = 0; i < nv; i++) d[i * 256 + tid] = s[i * 256 + tid];
    } else {  // fp32 -> bf16: float4 load, packed cvt, 8B store
      const f32x4* s = (const f32x4*)((const float*)src + base);
      uint2* d = (uint2*)(dst + base);
      for (int i = 0; i < nv; i++) {
        f32x4 v = s[i * 256 + tid];
        uint2 o; o.x = pkbf(v[0], v[1]); o.y = pkbf(v[2], v[3]);
        d[i * 256 + tid] = o;
      }
    }
    return;
  }
  // 64x64 fp32->bf16 transposes: in[R][C] -> out[C][R]
  const int t0 = id - 4099;
  const void* src; uint16_t* dst; int R, C, bx, by;
  if (t0 < 1024) {  // Wq/Wk/Wv/Wo, 256 tiles each (16x16)
    const int wsel = t0 >> 8, t = t0 & 255;
    const void* srcs[4] = {Wq, Wk, Wv, Wo};
    uint16_t* dsts[4] = {WqT, WkT, WvT, WoT};
    src = srcs[wsel]; dst = dsts[wsel]; R = 1024; C = 1024; bx = t & 15; by = t >> 4;
  } else if (t0 < 2048) { int t = t0 - 1024; src = W1; dst = W1T; R = 1024; C = 4096; bx = t & 63; by = t >> 6; }
  else                  { int t = t0 - 2048; src = W2; dst = W2T; R = 4096; C = 1024; bx = t & 15; by = t >> 4; }
  const uint16_t* u16 = (const uint16_t*)src;
  const float* f32 = (const float*)src;
  const bool is16 = sniff_is_bf16(u16, (int64_t)R * C, tid, &s_cnt);
  const int c0 = bx * 64, r0 = by * 64;
  if (is16) {
    const int c8 = (tid & 7) * 8, r = tid >> 3;
#pragma unroll
    for (int ri = 0; ri < 2; ri++) {
      const int row = r + ri * 32;
      u16x8 v = *(const u16x8*)(u16 + (int64_t)(r0 + row) * C + c0 + c8);
#pragma unroll
      for (int j = 0; j < 8; j++) tile[c8 + j][row] = v[j];
    }
  } else {
    const int c4 = (tid & 15) * 4, r = tid >> 4;
#pragma unroll
    for (int ri = 0; ri < 4; ri++) {
      const int row = r + ri * 16;
      f32x4 v = *(const f32x4*)(f32 + (int64_t)(r0 + row) * C + c0 + c4);
#pragma unroll
      for (int j = 0; j < 4; j++) tile[c4 + j][row] = f2bf(v[j]);
    }
  }
  __syncthreads();
  const int rr8 = (tid & 7) * 8, cc = tid >> 3;
#pragma unroll
  for (int ci = 0; ci < 2; ci++) {
    const int col = cc + ci * 32;
    *(u16x8*)(dst + (int64_t)(c0 + col) * R + r0 + rr8) = *(const u16x8*)&tile[col][rr8];
  }
}

// ---- per-batch V transpose (vectorized): KVb[b*2048+k][1024+c] -> Vt[b][c][k]
__global__ __launch_bounds__(256) void vtrans(
    const uint16_t* __restrict__ KVb, uint16_t* __restrict__ Vt) {
  __shared__ uint16_t tile[64][65];
  const int z = blockIdx.z;
  const uint16_t* in = KVb + (int64_t)z * 2048 * 2048 + 1024;
  uint16_t* out = Vt + (int64_t)z * 1024 * 2048;
  const int tid = threadIdx.x;
  const int c0 = blockIdx.x * 64, k0 = blockIdx.y * 64;
  const int c8 = (tid & 7) * 8, r = tid >> 3;
#pragma unroll
  for (int ri = 0; ri < 2; ri++) {
    const int krow = r + ri * 32;
    u16x8 v = *(const u16x8*)(in + (int64_t)(k0 + krow) * 2048 + c0 + c8);
#pragma unroll
    for (int j = 0; j < 8; j++) tile[c8 + j][krow] = v[j];
  }
  __syncthreads();
  const int k8 = (tid & 7) * 8, cc = tid >> 3;
#pragma unroll
  for (int ci = 0; ci < 2; ci++) {
    const int col = cc + ci * 32;
    *(u16x8*)(out + (int64_t)(c0 + col) * 2048 + k0 + k8) = *(const u16x8*)&tile[col][k8];
  }
}

enum { EPI_NONE = 0, EPI_BIAS_RES = 1, EPI_BIAS_GELU = 2 };

// ---------------- GEMM v4 (proven 128x128, serial stage) ------------------
#define BM 128
#define BN 128
#define BK 64

template <int EPI, int RESF32, int OUTF32, int SPLITK>
__device__ __forceinline__ void gemm_body(
    const uint16_t* __restrict__ A, const uint16_t* __restrict__ Bt,
    void* __restrict__ Cv, const uint16_t* __restrict__ bias,
    const void* __restrict__ resid, int M, int N, int K_total,
    int m0, int n0, int zslice, uint16_t* As, uint16_t* Bs) {
  const int tid = threadIdx.x;
  const int w = tid >> 6, l = tid & 63;
  const int wu = __builtin_amdgcn_readfirstlane(w);
  const int wm = (w >> 1) * 64, wn = (w & 1) * 64;
  const int ls = l & 15, lg = l >> 4;
  const int K = SPLITK ? (K_total >> 1) : K_total;
  const int kof = SPLITK ? zslice * K : 0;

  const int sr = 8 * w + (l >> 3);
  const int koff = (((l & 7) ^ ((l >> 3) & 7)) * 8);
  const uint16_t* Ag = A + (int64_t)(m0 + sr) * K_total + kof + koff;
  const uint16_t* Bg = Bt + (int64_t)(n0 + sr) * K_total + kof + koff;
  const int64_t rstep = (int64_t)32 * K_total;

  uint16_t* lA = As + wu * 512;
  uint16_t* lB = Bs + wu * 512;

  f32x4 acc[4][4] = {};

  for (int kb = 0; kb < K; kb += BK) {
    __syncthreads();
#pragma unroll
    for (int r = 0; r < 4; r++) {
      gload16(Ag + r * rstep + kb, lA + r * 2048);
      gload16(Bg + r * rstep + kb, lB + r * 2048);
    }
    __syncthreads();
#pragma unroll
    for (int kk = 0; kk < 2; kk++) {
      s16x8 af[4], bfr[4];
#pragma unroll
      for (int i = 0; i < 4; i++) {
        const int row = wm + i * 16 + ls;
        af[i] = *(const s16x8*)&As[row * 64 + (((kk * 4 + lg) ^ (ls & 7)) * 8)];
      }
#pragma unroll
      for (int j = 0; j < 4; j++) {
        const int row = wn + j * 16 + ls;
        bfr[j] = *(const s16x8*)&Bs[row * 64 + (((kk * 4 + lg) ^ (ls & 7)) * 8)];
      }
#pragma unroll
      for (int i = 0; i < 4; i++)
#pragma unroll
        for (int j = 0; j < 4; j++)
          acc[i][j] = __builtin_amdgcn_mfma_f32_16x16x32_bf16(af[i], bfr[j], acc[i][j], 0, 0, 0);
    }
  }

#pragma unroll
  for (int i = 0; i < 4; i++) {
#pragma unroll
    for (int rr = 0; rr < 4; rr++) {
      const int64_t row = m0 + wm + i * 16 + lg * 4 + rr;
#pragma unroll
      for (int j = 0; j < 4; j++) {
        const int col = n0 + wn + j * 16 + ls;
        float v = acc[i][j][rr];
        if (EPI == EPI_BIAS_RES) {
          if (!SPLITK || zslice == 0) {
            const float rv = RESF32 ? ((const float*)resid)[row * N + col]
                                    : bf2f(((const uint16_t*)resid)[row * N + col]);
            v += bf2f(bias[col]) + rv;
          }
        } else if (EPI == EPI_BIAS_GELU) {
          v += bf2f(bias[col]);
          v = gelu_exactf(v);
        }
        if (SPLITK)
          atomicAdd((float*)Cv + row * N + col, v);
        else if (OUTF32)
          ((float*)Cv)[row * N + col] = v;
        else
          ((uint16_t*)Cv)[row * N + col] = f2bf(v);
      }
    }
  }
}

template <int EPI, int RESF32, int OUTF32, int SPLITK>
__global__ __launch_bounds__(256, 3) void gemm_single(
    const uint16_t* __restrict__ A, const uint16_t* __restrict__ Bt,
    void* __restrict__ Cv, const uint16_t* __restrict__ bias,
    const void* __restrict__ resid, int M, int N, int K_total) {
  __shared__ alignas(16) uint16_t As[BM * BK];
  __shared__ alignas(16) uint16_t Bs[BN * BK];
  gemm_body<EPI, RESF32, OUTF32, SPLITK>(A, Bt, Cv, bias, resid, M, N, K_total,
                                         blockIdx.x * BM, blockIdx.y * BN,
                                         (int)blockIdx.z, As, Bs);
}

// ======= GEMM v6: 256x256 tile, BK=64, 8-wave, MINIMUM 2-PHASE pipeline ====
// T3 "minimum 2-phase" recipe: per K-tile t,
//   STAGE(buf^1, t+1)      <- issued FIRST (8 x global_load_lds, 64KB)
//   sched_barrier(0)       <- pin stage-issue before the reads (anti-sink)
//   ds_read cur (24 x b128, non-redundant) + 64 MFMA (2 kk halves)
//   __syncthreads()        <- one vmcnt(0)+lgkmcnt(0)+barrier per tile
// Double-buffered LDS 128KB (1 block/CU, 8 waves). HBM/L2 latency of the
// stage hides under the ~600cyc compute phase. Race-free: buf^1 holds tile
// t-1 whose reads completed before the previous barrier (lgkm before MFMA).
template <int EPI, int RESF32, int OUTF32, int SPLITK>
__device__ __forceinline__ void gemm2_body(
    const uint16_t* __restrict__ A, const uint16_t* __restrict__ Bt,
    void* __restrict__ Cv, const uint16_t* __restrict__ bias,
    const void* __restrict__ resid, int M, int N, int K_total,
    int m0, int n0, int zslice, uint16_t* As, uint16_t* Bs) {
  const int tid = threadIdx.x;
  const int w = tid >> 6, l = tid & 63;
  const int wu = __builtin_amdgcn_readfirstlane(w);
  const int ls = l & 15, lg = l >> 4;
  const int wm = (w >> 2) * 128, wn = (w & 3) * 64;  // 2M x 4N waves
  const int K = K_total / SPLITK;
  const int kof = zslice * K;
  const int NT = K / 64;

  // staging: quadrant q = 64 rows; this thread covers row q*64 + w*8 + l/8,
  // global col-chunk (l&7)^(row&7) -> linear LDS (XOR swizzle via source).
  const int srow = (w << 3) + (l >> 3);
  const int koff = (((l & 7) ^ ((l >> 3) & 7)) * 8);
  const uint16_t* Ag = A + (int64_t)(m0 + srow) * K_total + kof + koff;
  const uint16_t* Bg = Bt + (int64_t)(n0 + srow) * K_total + kof + koff;
  const int64_t cstep = (int64_t)64 * K_total;

  f32x4 acc[8][4] = {};

#define STAGE_T2(BB, KB)                                                    \
  do {                                                                      \
    _Pragma("unroll") for (int q_ = 0; q_ < 4; q_++) {                      \
      gload16(Ag + q_ * cstep + (KB), As + (BB) + q_ * 4096 + wu * 512);    \
      gload16(Bg + q_ * cstep + (KB), Bs + (BB) + q_ * 4096 + wu * 512);    \
    }                                                                       \
  } while (0)

  STAGE_T2(0, 0);
  __syncthreads();

  for (int t = 0; t < NT; ++t) {
    const int cb = (t & 1) << 14;   // current buf base (elements)
    const int nb = 16384 - cb;      // next buf
    if (t + 1 < NT) STAGE_T2(nb, (int64_t)(t + 1) * 64);
    __builtin_amdgcn_sched_barrier(0);  // keep stage-issue ahead of compute
#pragma unroll
    for (int kk = 0; kk < 2; kk++) {
      s16x8 af[8], bf_[4];
      const int x_ = ls & 7;
      const int ch = ((kk * 4 + lg) ^ x_) * 8;
#pragma unroll
      for (int i = 0; i < 8; i++)
        af[i] = *(const s16x8*)&As[cb + (wm + i * 16 + ls) * 64 + ch];
#pragma unroll
      for (int j = 0; j < 4; j++)
        bf_[j] = *(const s16x8*)&Bs[cb + (wn + j * 16 + ls) * 64 + ch];
#pragma unroll
      for (int i = 0; i < 8; i++)
#pragma unroll
        for (int j = 0; j < 4; j++)
          acc[i][j] = __builtin_amdgcn_mfma_f32_16x16x32_bf16(af[i], bf_[j], acc[i][j], 0, 0, 0);
    }
    __syncthreads();
  }
#undef STAGE_T2

#pragma unroll
  for (int i = 0; i < 8; i++) {
#pragma unroll
    for (int rr = 0; rr < 4; rr++) {
      const int64_t row = m0 + wm + i * 16 + lg * 4 + rr;
#pragma unroll
      for (int j = 0; j < 4; j++) {
        const int col = n0 + wn + j * 16 + ls;
        float v = acc[i][j][rr];
        if (EPI == EPI_BIAS_RES) {
          if (SPLITK == 1 || zslice == 0) {
            const float rv = RESF32 ? ((const float*)resid)[row * N + col]
                                    : bf2f(((const uint16_t*)resid)[row * N + col]);
            v += bf2f(bias[col]) + rv;
          }
        } else if (EPI == EPI_BIAS_GELU) {
          v += bf2f(bias[col]);
          v = gelu_exactf(v);
        }
        if (SPLITK > 1)
          atomicAdd((float*)Cv + row * N + col, v);
        else if (OUTF32)
          ((float*)Cv)[row * N + col] = v;
        else
          ((uint16_t*)Cv)[row * N + col] = f2bf(v);
      }
    }
  }
}

template <int EPI, int RESF32, int OUTF32, int SPLITK>
__global__ __launch_bounds__(512, 2) void gemm2_single(
    const uint16_t* __restrict__ A, const uint16_t* __restrict__ Bt,
    void* __restrict__ Cv, const uint16_t* __restrict__ bias,
    const void* __restrict__ resid, int M, int N, int K_total) {
  __shared__ alignas(16) uint16_t As[2 * 16384];  // 64KB
  __shared__ alignas(16) uint16_t Bs[2 * 16384];  // 64KB
  gemm2_body<EPI, RESF32, OUTF32, SPLITK>(A, Bt, Cv, bias, resid, M, N, K_total,
                                          blockIdx.x * 256, blockIdx.y * 256,
                                          (int)blockIdx.z, As, Bs);
}

// grouped Q-proj + KV-proj at 256x256 2-phase: blocks [0,256) KV, [256,320) Q.
__global__ __launch_bounds__(512, 2) void gemm2_qkv(
    const uint16_t* __restrict__ xA, const uint16_t* __restrict__ WqT,
    uint16_t* __restrict__ Qb,
    const uint16_t* __restrict__ ctxA, const uint16_t* __restrict__ KVWt,
    uint16_t* __restrict__ KVb) {
  __shared__ alignas(16) uint16_t As[2 * 16384];
  __shared__ alignas(16) uint16_t Bs[2 * 16384];
  const int id = blockIdx.x;
  if (id < 256) {
    gemm2_body<EPI_NONE, 0, 0, 1>(ctxA, KVWt, KVb, nullptr, nullptr, 8192, 2048, 1024,
                                  (id & 31) * 256, (id >> 5) * 256, 0, As, Bs);
  } else {
    const int t = id - 256;
    gemm2_body<EPI_NONE, 0, 0, 1>(xA, WqT, Qb, nullptr, nullptr, 4096, 1024, 1024,
                                  (t & 15) * 256, (t >> 4) * 256, 0, As, Bs);
  }
}

// ---------------- flash cross-attention v5 (unchanged) --------------------
#define KLD 72
#define PLD 72

__global__ __launch_bounds__(256, 2) void attn_kernel(
    const uint16_t* __restrict__ Q,   // [B*1024][1024]
    const uint16_t* __restrict__ KV,  // [B*2048][2048]; cols 0..1023 = K
    const uint16_t* __restrict__ Vt,  // [B][1024 (h*64+d)][2048 (key)]
    uint16_t* __restrict__ O) {       // [B*1024][1024]
  __shared__ alignas(16) uint16_t Ks[64 * KLD];
  __shared__ alignas(16) uint16_t Vts[64 * KLD];
  __shared__ alignas(16) uint16_t Ps[8][16 * PLD];  // [w*2+qq]

  const int tid = threadIdx.x;
  const int w = tid >> 6, l = tid & 63;
  const int ls = l & 15, lg = l >> 4;

  const int blk = blockIdx.x;
  const int bh = blk & 63;
  const int qb = blk >> 6;
  const int h = bh & 15, b = bh >> 4;

  const int64_t qrow0 = (int64_t)b * 1024 + qb * 128;
  const int hoff = h * 64;
  const uint16_t* Vtb = Vt + (int64_t)b * 1024 * 2048;

  const float sc = 0.125f * 1.4426950408889634f;  // scale * log2(e)

  s16x8 qf[2][2];
#pragma unroll
  for (int qq = 0; qq < 2; qq++)
#pragma unroll
    for (int ks = 0; ks < 2; ks++) {
      s16x8 r = *(const s16x8*)(Q + (qrow0 + w * 32 + qq * 16 + ls) * 1024 + hoff + ks * 32 + lg * 8);
#pragma unroll
      for (int j = 0; j < 8; j++)
        qf[qq][ks][j] = (short)f2bf(bf2f((uint16_t)r[j]) * sc);
    }

  f32x4 oacc[2][4] = {};
  float lsum[2] = {0.f, 0.f};

  const int srow = tid >> 3;
  const int sc8 = (tid & 7) * 8;
  const uint16_t* Kg = KV + ((int64_t)b * 2048 + srow) * 2048 + hoff + sc8;
  const uint16_t* Vg = Vtb + (int64_t)(hoff + srow) * 2048 + sc8;

  s16x8 rk0 = *(const s16x8*)(Kg);
  s16x8 rk1 = *(const s16x8*)(Kg + (int64_t)32 * 2048);
  s16x8 rv0 = *(const s16x8*)(Vg);
  s16x8 rv1 = *(const s16x8*)(Vg + (int64_t)32 * 2048);

  for (int kt = 0; kt < 2048; kt += 64) {
    __syncthreads();
    *(s16x8*)&Ks[srow * KLD + sc8] = rk0;
    *(s16x8*)&Ks[(srow + 32) * KLD + sc8] = rk1;
    *(s16x8*)&Vts[srow * KLD + sc8] = rv0;
    *(s16x8*)&Vts[(srow + 32) * KLD + sc8] = rv1;
    const int ktn = kt + 64;
    if (ktn < 2048) {
      rk0 = *(const s16x8*)(Kg + (int64_t)ktn * 2048);
      rk1 = *(const s16x8*)(Kg + (int64_t)(ktn + 32) * 2048);
      rv0 = *(const s16x8*)(Vg + ktn);
      rv1 = *(const s16x8*)(Vg + ktn + (int64_t)32 * 2048);
    }
    __syncthreads();

    f32x4 st[2][4];
#pragma unroll
    for (int jn = 0; jn < 4; jn++) {
      f32x4 z = {0.f, 0.f, 0.f, 0.f};
      st[0][jn] = z; st[1][jn] = z;
#pragma unroll
      for (int ks = 0; ks < 2; ks++) {
        s16x8 kf = *(const s16x8*)&Ks[(jn * 16 + ls) * KLD + ks * 32 + lg * 8];
        st[0][jn] = __builtin_amdgcn_mfma_f32_16x16x32_bf16(kf, qf[0][ks], st[0][jn], 0, 0, 0);
        st[1][jn] = __builtin_amdgcn_mfma_f32_16x16x32_bf16(kf, qf[1][ks], st[1][jn], 0, 0, 0);
      }
    }

#pragma unroll
    for (int qq = 0; qq < 2; qq++)
#pragma unroll
      for (int jn = 0; jn < 4; jn++) {
        const float p0 = exp2f(st[qq][jn][0]);
        const float p1 = exp2f(st[qq][jn][1]);
        const float p2 = exp2f(st[qq][jn][2]);
        const float p3 = exp2f(st[qq][jn][3]);
        lsum[qq] += (p0 + p1) + (p2 + p3);
        uint2 pk; pk.x = pkbf(p0, p1); pk.y = pkbf(p2, p3);
        *(uint2*)&Ps[w * 2 + qq][ls * PLD + jn * 16 + lg * 4] = pk;
      }

#pragma unroll
    for (int ks = 0; ks < 2; ks++) {
      s16x8 pf0 = *(const s16x8*)&Ps[w * 2 + 0][ls * PLD + ks * 32 + lg * 8];
      s16x8 pf1 = *(const s16x8*)&Ps[w * 2 + 1][ls * PLD + ks * 32 + lg * 8];
#pragma unroll
      for (int jn = 0; jn < 4; jn++) {
        s16x8 vf = *(const s16x8*)&Vts[(jn * 16 + ls) * KLD + ks * 32 + lg * 8];
        oacc[0][jn] = __builtin_amdgcn_mfma_f32_16x16x32_bf16(pf0, vf, oacc[0][jn], 0, 0, 0);
        oacc[1][jn] = __builtin_amdgcn_mfma_f32_16x16x32_bf16(pf1, vf, oacc[1][jn], 0, 0, 0);
      }
    }
  }

#pragma unroll
  for (int qq = 0; qq < 2; qq++) {
    float red = lsum[qq];
    red += __shfl_xor(red, 16, 64);
    red += __shfl_xor(red, 32, 64);
#pragma unroll
    for (int rr = 0; rr < 4; rr++) {
      const float inv = 1.0f / __shfl(red, lg * 4 + rr, 64);
      const int64_t row = qrow0 + w * 32 + qq * 16 + lg * 4 + rr;
#pragma unroll
      for (int jn = 0; jn < 4; jn++)
        O[row * 1024 + hoff + jn * 16 + ls] = f2bf(oacc[qq][jn][rr] * inv);
    }
  }
}

// ---------------- host ----------------
extern "C" void kernel_launch(void* const* d_in, const int* in_sizes, int n_in,
                              void* d_out, int out_size, void* d_ws, size_t ws_size,
                              hipStream_t stream) {
  const void* x_raw   = d_in[0];
  const void* ctx_raw = d_in[1];
  const void* Wq_raw  = d_in[2];
  const void* Wk_raw  = d_in[3];
  const void* Wv_raw  = d_in[4];
  const void* Wo_raw  = d_in[5];
  const void* bo_raw  = d_in[6];
  const void* W1_raw  = d_in[7];
  const void* b1_raw  = d_in[8];
  const void* W2_raw  = d_in[9];
  const void* b2_raw  = d_in[10];

  const int64_t Mi = 1 << 20;
  uint16_t* ws   = (uint16_t*)d_ws;
  uint16_t* WqT  = ws;                  // [0,1M)
  uint16_t* KVWt = ws + 1 * Mi;         // [1M,3M)  [2048][1024] = [WkT;WvT]
  uint16_t* WoT  = ws + 3 * Mi;         // [3M,4M)
  uint16_t* W1T  = ws + 4 * Mi;         // [4M,8M)   [4096][1024]
  uint16_t* W2T  = ws + 8 * Mi;         // [8M,12M)  [1024][4096]
  uint16_t* bob  = ws + 12 * Mi;
  uint16_t* b1b  = ws + 12 * Mi + 1024;
  uint16_t* b2b  = ws + 12 * Mi + 5120;
  uint16_t* xb   = ws + 13 * Mi;        // [13M,17M) dead after Q-proj
  uint16_t* AO   = ws + 13 * Mi;        // alias xb (born in attention)
  uint16_t* ctxb = ws + 17 * Mi;        // [17M,25M) dead after KV-proj
  uint16_t* Vt   = ws + 17 * Mi;        // alias ctxb (born after KV-proj)
  uint16_t* X1   = ws + 17 * Mi;        // alias Vt (born after attention)
  uint16_t* Qb   = ws + 25 * Mi;        // [25M,29M)
  uint16_t* KVb  = ws + 29 * Mi;        // [29M,45M) [8192][2048]; dead after attn
  uint16_t* Hb   = ws + 29 * Mi;        // alias KVb (born at FF1)
  // peak ws: 45M elements = 90 MB

  const dim3 tb(256);
  const dim3 tb8(512);
  // one fused prep dispatch (vectorized): zero + converts + 6 transposes
  prep_all<<<dim3(7171), tb, 0, stream>>>(
      (float*)d_out,
      x_raw, ctx_raw, bo_raw, b1_raw, b2_raw,
      Wq_raw, Wk_raw, Wv_raw, Wo_raw, W1_raw, W2_raw,
      xb, ctxb, bob, b1b, b2b,
      WqT, KVWt, KVWt + Mi, WoT, W1T, W2T);

  // grouped Q-proj + fused KV-proj, 256^2 2-phase (320 blocks x 8 waves)
  gemm2_qkv<<<dim3(320), tb8, 0, stream>>>(xb, WqT, Qb, ctxb, KVWt, KVb);

  // per-batch V transpose (vectorized 64x64 tiles)
  vtrans<<<dim3(16, 32, 4), tb, 0, stream>>>(KVb, Vt);

  attn_kernel<<<dim3(512), tb, 0, stream>>>(Qb, KVb, Vt, AO);

  // out-proj + bias + residual(x, fp32 direct): N=1024 -> keep proven 128^2
  gemm_single<EPI_BIAS_RES, 1, 0, 0><<<dim3(32, 8), tb, 0, stream>>>(
      AO, WoT, X1, bob, x_raw, 4096, 1024, 1024);
  // FF1 + bias + exact GELU (fast erf): 256 blocks, 256^2 2-phase
  gemm2_single<EPI_BIAS_GELU, 0, 0, 1><<<dim3(16, 16), tb8, 0, stream>>>(
      X1, W1T, Hb, b1b, nullptr, 4096, 4096, 1024);
  // FF2 + bias + residual(X1): proven 128^2 split-K2, fp32 atomics into
  // pre-zeroed d_out
  gemm_single<EPI_BIAS_RES, 0, 1, 1><<<dim3(32, 8, 2), tb, 0, stream>>>(
      Hb, W2T, d_out, b2b, X1, 4096, 1024, 4096);
}